// Round 1
// baseline (527.266 us; speedup 1.0000x reference)
//
#include <hip/hip_runtime.h>
#include <math.h>

#define DD 128
#define HH 16
#define EPSV 1e-5f

// ---------------- CSR build ----------------

__global__ void k_hist(const int* __restrict__ dst, int* __restrict__ deg, int ecnt) {
  int e = blockIdx.x * blockDim.x + threadIdx.x;
  if (e < ecnt) atomicAdd(&deg[dst[e]], 1);
}

__global__ void k_dinv(const int* __restrict__ deg, float* __restrict__ dinv, int n) {
  int i = blockIdx.x * blockDim.x + threadIdx.x;
  if (i < n) dinv[i] = rsqrtf((float)deg[i] + 2.0f);
}

#define SCAN_T 1024
#define SCAN_I 4

__global__ void k_scan1(const int* __restrict__ deg, int* __restrict__ bsum, int n) {
  __shared__ int sh[SCAN_T];
  int tid = threadIdx.x;
  int base = blockIdx.x * SCAN_T * SCAN_I + tid * SCAN_I;
  int s = 0;
#pragma unroll
  for (int j = 0; j < SCAN_I; ++j) { int i = base + j; if (i < n) s += deg[i]; }
  sh[tid] = s;
  __syncthreads();
  for (int off = SCAN_T / 2; off > 0; off >>= 1) {
    if (tid < off) sh[tid] += sh[tid + off];
    __syncthreads();
  }
  if (tid == 0) bsum[blockIdx.x] = sh[0];
}

__global__ void k_scan2(const int* __restrict__ deg, const int* __restrict__ bsum,
                        int* __restrict__ rowoff, int n) {
  __shared__ int sh[SCAN_T];
  __shared__ int sbase;
  int tid = threadIdx.x;
  int b = blockIdx.x;
  if (tid == 0) { int s = 0; for (int j = 0; j < b; ++j) s += bsum[j]; sbase = s; }
  int base = b * SCAN_T * SCAN_I + tid * SCAN_I;
  int d[SCAN_I]; int ts = 0;
#pragma unroll
  for (int j = 0; j < SCAN_I; ++j) { int i = base + j; d[j] = (i < n) ? deg[i] : 0; ts += d[j]; }
  sh[tid] = ts;
  __syncthreads();
  for (int off = 1; off < SCAN_T; off <<= 1) {
    int v = (tid >= off) ? sh[tid - off] : 0;
    __syncthreads();
    sh[tid] += v;
    __syncthreads();
  }
  int ex = sbase + sh[tid] - ts;  // exclusive prefix for this thread's first item
#pragma unroll
  for (int j = 0; j < SCAN_I; ++j) {
    int i = base + j;
    if (i < n) rowoff[i] = ex;
    ex += d[j];
  }
}

__global__ void k_fill(const int* __restrict__ src, const int* __restrict__ dst,
                       const float* __restrict__ dinv, const int* __restrict__ rowoff,
                       int* __restrict__ cursor, int* __restrict__ csr_s,
                       float* __restrict__ csr_n, int ecnt) {
  int e = blockIdx.x * blockDim.x + threadIdx.x;
  if (e >= ecnt) return;
  int s = src[e], d = dst[e];
  int p = atomicAdd(&cursor[d], 1);
  int idx = rowoff[d] + p;
  csr_s[idx] = s;
  csr_n[idx] = dinv[s] * dinv[d];
}

// ---------------- GEMM: C[nrows,128] = A[nrows,128] @ B[128,128] ----------------
// grid (ceil(nrows/128), 2), block 256. Per block: 128 rows x 64 cols.
// B-half (32KB) staged in LDS; A rows read as float4 through L1.

__global__ __launch_bounds__(256) void k_gemm(const float* __restrict__ A,
                                              const float* __restrict__ B,
                                              float* __restrict__ C, int nrows) {
  __shared__ float Bs[DD * 64];
  int tid = threadIdx.x;
  int tx = tid & 15, ty = tid >> 4;
  int rowbase = blockIdx.x * 128;
  int c0 = blockIdx.y * 64;
  {
    int kk = tid >> 4;
    int cc = (tid & 15) * 4;
#pragma unroll
    for (int p = 0; p < 8; ++p) {
      int k = p * 16 + kk;
      float4 bv = *reinterpret_cast<const float4*>(&B[k * DD + c0 + cc]);
      *reinterpret_cast<float4*>(&Bs[k * 64 + cc]) = bv;
    }
  }
  __syncthreads();
  float acc[8][4];
#pragma unroll
  for (int i = 0; i < 8; ++i)
#pragma unroll
    for (int j = 0; j < 4; ++j) acc[i][j] = 0.f;
  int rl[8];
#pragma unroll
  for (int i = 0; i < 8; ++i) {
    int r = rowbase + ty * 8 + i;
    rl[i] = (r < nrows) ? r : (nrows - 1);
  }
  const float4* A4 = reinterpret_cast<const float4*>(A);
  for (int kq = 0; kq < 32; ++kq) {
    float4 av[8];
#pragma unroll
    for (int i = 0; i < 8; ++i) av[i] = A4[(size_t)rl[i] * 32 + kq];
#pragma unroll
    for (int j = 0; j < 4; ++j) {
      float4 bv = *reinterpret_cast<const float4*>(&Bs[(kq * 4 + j) * 64 + tx * 4]);
#pragma unroll
      for (int i = 0; i < 8; ++i) {
        float a = (j == 0) ? av[i].x : (j == 1) ? av[i].y : (j == 2) ? av[i].z : av[i].w;
        acc[i][0] = fmaf(a, bv.x, acc[i][0]);
        acc[i][1] = fmaf(a, bv.y, acc[i][1]);
        acc[i][2] = fmaf(a, bv.z, acc[i][2]);
        acc[i][3] = fmaf(a, bv.w, acc[i][3]);
      }
    }
  }
  int cbase = c0 + tx * 4;
#pragma unroll
  for (int i = 0; i < 8; ++i) {
    int r = rowbase + ty * 8 + i;
    if (r < nrows) {
      float4 o;
      o.x = acc[i][0]; o.y = acc[i][1]; o.z = acc[i][2]; o.w = acc[i][3];
      *reinterpret_cast<float4*>(&C[(size_t)r * DD + cbase]) = o;
    }
  }
}

// ---------------- Aggregation + LN (+ReLU) ----------------
// block = 128 threads = one node; thread t owns dim t.

__global__ __launch_bounds__(128) void k_agg_ln_relu(
    const float* __restrict__ xw, const int* __restrict__ csr_s,
    const float* __restrict__ csr_n, const int* __restrict__ rowoff,
    const int* __restrict__ deg, const float* __restrict__ dinv,
    const float* __restrict__ bias, const float* __restrict__ gam,
    const float* __restrict__ bet, float* __restrict__ outp, int n) {
  int i = blockIdx.x;
  int t = threadIdx.x;
  int start = rowoff[i];
  int cnt = deg[i];
  float di = dinv[i];
  float acc = xw[(size_t)i * DD + t] * (2.f * di * di) + bias[t];
  int e = start, end = start + cnt;
  for (; e + 4 <= end; e += 4) {
    int s0 = csr_s[e], s1 = csr_s[e + 1], s2 = csr_s[e + 2], s3 = csr_s[e + 3];
    float n0 = csr_n[e], n1 = csr_n[e + 1], n2 = csr_n[e + 2], n3 = csr_n[e + 3];
    float v0 = xw[(size_t)s0 * DD + t], v1 = xw[(size_t)s1 * DD + t];
    float v2 = xw[(size_t)s2 * DD + t], v3 = xw[(size_t)s3 * DD + t];
    acc = fmaf(v0, n0, acc);
    acc = fmaf(v1, n1, acc);
    acc = fmaf(v2, n2, acc);
    acc = fmaf(v3, n3, acc);
  }
  for (; e < end; ++e) acc = fmaf(xw[(size_t)csr_s[e] * DD + t], csr_n[e], acc);
  // LayerNorm over the 128 dims (two-pass for accuracy)
  __shared__ float red[4];
  float s = acc;
#pragma unroll
  for (int off = 32; off > 0; off >>= 1) s += __shfl_xor(s, off);
  int wid = t >> 6;
  if ((t & 63) == 0) red[wid] = s;
  __syncthreads();
  float mu = (red[0] + red[1]) * (1.f / DD);
  float c = acc - mu;
  float q = c * c;
#pragma unroll
  for (int off = 32; off > 0; off >>= 1) q += __shfl_xor(q, off);
  if ((t & 63) == 0) red[2 + wid] = q;
  __syncthreads();
  float var = (red[2] + red[3]) * (1.f / DD);
  float h = c * rsqrtf(var + EPSV) * gam[t] + bet[t];
  outp[(size_t)i * DD + t] = fmaxf(h, 0.f);
}

// agg2 + LN + SE gate + residual + relu, fully fused
__global__ __launch_bounds__(128) void k_agg_ln_se(
    const float* __restrict__ xw, const int* __restrict__ csr_s,
    const float* __restrict__ csr_n, const int* __restrict__ rowoff,
    const int* __restrict__ deg, const float* __restrict__ dinv,
    const float* __restrict__ bias, const float* __restrict__ gam,
    const float* __restrict__ bet, const float* __restrict__ Ws,
    const float* __restrict__ bs, const float* __restrict__ We,
    const float* __restrict__ be, const float* __restrict__ xin,
    float* __restrict__ outp, int n) {
  int i = blockIdx.x;
  int t = threadIdx.x;
  int start = rowoff[i];
  int cnt = deg[i];
  float di = dinv[i];
  float acc = xw[(size_t)i * DD + t] * (2.f * di * di) + bias[t];
  int e = start, end = start + cnt;
  for (; e + 4 <= end; e += 4) {
    int s0 = csr_s[e], s1 = csr_s[e + 1], s2 = csr_s[e + 2], s3 = csr_s[e + 3];
    float n0 = csr_n[e], n1 = csr_n[e + 1], n2 = csr_n[e + 2], n3 = csr_n[e + 3];
    float v0 = xw[(size_t)s0 * DD + t], v1 = xw[(size_t)s1 * DD + t];
    float v2 = xw[(size_t)s2 * DD + t], v3 = xw[(size_t)s3 * DD + t];
    acc = fmaf(v0, n0, acc);
    acc = fmaf(v1, n1, acc);
    acc = fmaf(v2, n2, acc);
    acc = fmaf(v3, n3, acc);
  }
  for (; e < end; ++e) acc = fmaf(xw[(size_t)csr_s[e] * DD + t], csr_n[e], acc);
  // LayerNorm
  __shared__ float red[4];
  float s = acc;
#pragma unroll
  for (int off = 32; off > 0; off >>= 1) s += __shfl_xor(s, off);
  int wid = t >> 6;
  if ((t & 63) == 0) red[wid] = s;
  __syncthreads();
  float mu = (red[0] + red[1]) * (1.f / DD);
  float c = acc - mu;
  float q = c * c;
#pragma unroll
  for (int off = 32; off > 0; off >>= 1) q += __shfl_xor(q, off);
  if ((t & 63) == 0) red[2 + wid] = q;
  __syncthreads();
  float var = (red[2] + red[3]) * (1.f / DD);
  float h = c * rsqrtf(var + EPSV) * gam[t] + bet[t];  // no relu here
  // SE gate: s16 = relu(h . Ws + bs); w = sigmoid(s16 . We + be)
  float pj[HH];
#pragma unroll
  for (int j = 0; j < HH; ++j) pj[j] = h * Ws[t * HH + j];
#pragma unroll
  for (int off = 32; off > 0; off >>= 1) {
#pragma unroll
    for (int j = 0; j < HH; ++j) pj[j] += __shfl_xor(pj[j], off);
  }
  __shared__ float sred[2][HH];
  if ((t & 63) == 0) {
#pragma unroll
    for (int j = 0; j < HH; ++j) sred[wid][j] = pj[j];
  }
  __syncthreads();
  float wacc = be[t];
#pragma unroll
  for (int j = 0; j < HH; ++j) {
    float sj = sred[0][j] + sred[1][j] + bs[j];
    sj = fmaxf(sj, 0.f);
    wacc = fmaf(sj, We[j * DD + t], wacc);
  }
  float wgt = 1.f / (1.f + __expf(-wacc));
  outp[(size_t)i * DD + t] = fmaxf(fmaf(h, wgt, xin[(size_t)i * DD + t]), 0.f);
}

// ---------------- launcher ----------------

extern "C" void kernel_launch(void* const* d_in, const int* in_sizes, int n_in,
                              void* d_out, int out_size, void* d_ws, size_t ws_size,
                              hipStream_t stream) {
  const float* x   = (const float*)d_in[0];
  const int*   ei  = (const int*)d_in[1];
  const float* W1  = (const float*)d_in[2];
  const float* b1  = (const float*)d_in[3];
  const float* g1  = (const float*)d_in[4];
  const float* be1 = (const float*)d_in[5];
  const float* W2  = (const float*)d_in[6];
  const float* b2  = (const float*)d_in[7];
  const float* g2  = (const float*)d_in[8];
  const float* be2 = (const float*)d_in[9];
  const float* Ws  = (const float*)d_in[10];
  const float* bs  = (const float*)d_in[11];
  const float* We  = (const float*)d_in[12];
  const float* bee = (const float*)d_in[13];
  float* outp = (float*)d_out;

  int n    = in_sizes[0] / DD;
  int ecnt = in_sizes[1] / 2;
  const int* src = ei;
  const int* dst = ei + ecnt;

  char* w = (char*)d_ws;
  float* xw     = (float*)w; w += (size_t)n * DD * 4;
  float* h1     = (float*)w; w += (size_t)n * DD * 4;
  int*   deg    = (int*)w;   w += (size_t)n * 4;
  int*   cursor = (int*)w;   w += (size_t)n * 4;   // adjacent to deg (one memset)
  int*   rowoff = (int*)w;   w += (size_t)n * 4;
  float* dinv   = (float*)w; w += (size_t)n * 4;
  int*   bsum   = (int*)w;   w += 64 * 4;
  int*   csr_s  = (int*)w;   w += (size_t)ecnt * 4;
  float* csr_n  = (float*)w; w += (size_t)ecnt * 4;

  hipMemsetAsync(deg, 0, (size_t)n * 8, stream);  // deg + cursor

  const int TB = 256;
  int eb = (ecnt + TB - 1) / TB;
  int nbk = (n + TB - 1) / TB;
  k_hist<<<eb, TB, 0, stream>>>(dst, deg, ecnt);
  k_dinv<<<nbk, TB, 0, stream>>>(deg, dinv, n);
  int nb = (n + SCAN_T * SCAN_I - 1) / (SCAN_T * SCAN_I);
  k_scan1<<<nb, SCAN_T, 0, stream>>>(deg, bsum, n);
  k_scan2<<<nb, SCAN_T, 0, stream>>>(deg, bsum, rowoff, n);
  k_fill<<<eb, TB, 0, stream>>>(src, dst, dinv, rowoff, cursor, csr_s, csr_n, ecnt);

  dim3 gg((n + 127) / 128, 2);
  k_gemm<<<gg, 256, 0, stream>>>(x, W1, xw, n);
  k_agg_ln_relu<<<n, DD, 0, stream>>>(xw, csr_s, csr_n, rowoff, deg, dinv, b1, g1, be1, h1, n);
  k_gemm<<<gg, 256, 0, stream>>>(h1, W2, xw, n);
  k_agg_ln_se<<<n, DD, 0, stream>>>(xw, csr_s, csr_n, rowoff, deg, dinv, b2, g2, be2,
                                    Ws, bs, We, bee, x, outp, n);
}

// Round 2
// 460.325 us; speedup vs baseline: 1.1454x; 1.1454x over previous
//
#include <hip/hip_runtime.h>
#include <math.h>

#define DD 128
#define HH 16
#define EPSV 1e-5f

static __device__ __forceinline__ ushort f2bf(float f) {
  uint u = __float_as_uint(f);
  u += 0x7FFFu + ((u >> 16) & 1u);
  return (ushort)(u >> 16);
}

// ---------------- CSR build ----------------

__global__ void k_hist(const int* __restrict__ dst, int* __restrict__ deg, int ecnt) {
  int e = blockIdx.x * blockDim.x + threadIdx.x;
  if (e < ecnt) atomicAdd(&deg[dst[e]], 1);
}

__global__ void k_dinv(const int* __restrict__ deg, float* __restrict__ dinv, int n) {
  int i = blockIdx.x * blockDim.x + threadIdx.x;
  if (i < n) dinv[i] = rsqrtf((float)deg[i] + 2.0f);
}

#define SCAN_T 1024
#define SCAN_I 4

__global__ void k_scan1(const int* __restrict__ deg, int* __restrict__ bsum, int n) {
  __shared__ int sh[SCAN_T];
  int tid = threadIdx.x;
  int base = blockIdx.x * SCAN_T * SCAN_I + tid * SCAN_I;
  int s = 0;
#pragma unroll
  for (int j = 0; j < SCAN_I; ++j) { int i = base + j; if (i < n) s += deg[i]; }
  sh[tid] = s;
  __syncthreads();
  for (int off = SCAN_T / 2; off > 0; off >>= 1) {
    if (tid < off) sh[tid] += sh[tid + off];
    __syncthreads();
  }
  if (tid == 0) bsum[blockIdx.x] = sh[0];
}

__global__ void k_scan2(const int* __restrict__ deg, const int* __restrict__ bsum,
                        int* __restrict__ rowoff, int n) {
  __shared__ int sh[SCAN_T];
  __shared__ int sbase;
  int tid = threadIdx.x;
  int b = blockIdx.x;
  if (tid == 0) { int s = 0; for (int j = 0; j < b; ++j) s += bsum[j]; sbase = s; }
  int base = b * SCAN_T * SCAN_I + tid * SCAN_I;
  int d[SCAN_I]; int ts = 0;
#pragma unroll
  for (int j = 0; j < SCAN_I; ++j) { int i = base + j; d[j] = (i < n) ? deg[i] : 0; ts += d[j]; }
  sh[tid] = ts;
  __syncthreads();
  for (int off = 1; off < SCAN_T; off <<= 1) {
    int v = (tid >= off) ? sh[tid - off] : 0;
    __syncthreads();
    sh[tid] += v;
    __syncthreads();
  }
  int ex = sbase + sh[tid] - ts;
#pragma unroll
  for (int j = 0; j < SCAN_I; ++j) {
    int i = base + j;
    if (i < n) rowoff[i] = ex;
    ex += d[j];
  }
}

__global__ void k_fill(const int* __restrict__ src, const int* __restrict__ dst,
                       const int* __restrict__ rowoff, int* __restrict__ cursor,
                       int* __restrict__ csr_s, int ecnt) {
  int e = blockIdx.x * blockDim.x + threadIdx.x;
  if (e >= ecnt) return;
  int s = src[e], d = dst[e];
  int p = atomicAdd(&cursor[d], 1);
  csr_s[rowoff[d] + p] = s;
}

// ---------------- GEMM: C_bf16[nrows,128] = A_f32[nrows,128] @ B[128,128] ----------------

__global__ __launch_bounds__(256) void k_gemm(const float* __restrict__ A,
                                              const float* __restrict__ B,
                                              ushort* __restrict__ C, int nrows) {
  __shared__ float Bs[DD * 64];
  int tid = threadIdx.x;
  int tx = tid & 15, ty = tid >> 4;
  int rowbase = blockIdx.x * 128;
  int c0 = blockIdx.y * 64;
  {
    int kk = tid >> 4;
    int cc = (tid & 15) * 4;
#pragma unroll
    for (int p = 0; p < 8; ++p) {
      int k = p * 16 + kk;
      float4 bv = *reinterpret_cast<const float4*>(&B[k * DD + c0 + cc]);
      *reinterpret_cast<float4*>(&Bs[k * 64 + cc]) = bv;
    }
  }
  __syncthreads();
  float acc[8][4];
#pragma unroll
  for (int i = 0; i < 8; ++i)
#pragma unroll
    for (int j = 0; j < 4; ++j) acc[i][j] = 0.f;
  int rl[8];
#pragma unroll
  for (int i = 0; i < 8; ++i) {
    int r = rowbase + ty * 8 + i;
    rl[i] = (r < nrows) ? r : (nrows - 1);
  }
  const float4* A4 = reinterpret_cast<const float4*>(A);
  for (int kq = 0; kq < 32; ++kq) {
    float4 av[8];
#pragma unroll
    for (int i = 0; i < 8; ++i) av[i] = A4[(size_t)rl[i] * 32 + kq];
#pragma unroll
    for (int j = 0; j < 4; ++j) {
      float4 bv = *reinterpret_cast<const float4*>(&Bs[(kq * 4 + j) * 64 + tx * 4]);
#pragma unroll
      for (int i = 0; i < 8; ++i) {
        float a = (j == 0) ? av[i].x : (j == 1) ? av[i].y : (j == 2) ? av[i].z : av[i].w;
        acc[i][0] = fmaf(a, bv.x, acc[i][0]);
        acc[i][1] = fmaf(a, bv.y, acc[i][1]);
        acc[i][2] = fmaf(a, bv.z, acc[i][2]);
        acc[i][3] = fmaf(a, bv.w, acc[i][3]);
      }
    }
  }
  int cbase = c0 + tx * 4;
#pragma unroll
  for (int i = 0; i < 8; ++i) {
    int r = rowbase + ty * 8 + i;
    if (r < nrows) {
      ushort4 o;
      o.x = f2bf(acc[i][0]); o.y = f2bf(acc[i][1]);
      o.z = f2bf(acc[i][2]); o.w = f2bf(acc[i][3]);
      *reinterpret_cast<ushort4*>(&C[(size_t)r * DD + cbase]) = o;
    }
  }
}

// ---------------- agg1: gather bf16 + self + bias + LN + ReLU -> fp32 h1 ----------------
// 256 threads = 4 waves = 4 nodes. Lane t owns dims {2t, 2t+1}.

__global__ __launch_bounds__(256) void k_agg1(
    const ushort* __restrict__ xw, const int* __restrict__ csr_s,
    const int* __restrict__ rowoff, const int* __restrict__ deg,
    const float* __restrict__ dinv, const float* __restrict__ bias,
    const float* __restrict__ gam, const float* __restrict__ bet,
    float* __restrict__ outp, int n) {
  int wv = threadIdx.x >> 6, lane = threadIdx.x & 63;
  int i = blockIdx.x * 4 + wv;
  if (i >= n) return;
  int start = rowoff[i], cnt = deg[i];
  float di = dinv[i];
  const uint* xw32 = (const uint*)xw;  // row i at i*64 + lane, 2 bf16 per uint
  float2 bv = ((const float2*)bias)[lane];
  uint su = xw32[(size_t)i * 64 + lane];
  float sw = 2.f * di * di;
  float acc0 = fmaf(__uint_as_float(su << 16), sw, bv.x);
  float acc1 = fmaf(__uint_as_float(su & 0xFFFF0000u), sw, bv.y);
  int e = start, end = start + cnt;
  for (; e + 8 <= end; e += 8) {
    int s[8]; float nw[8]; uint v[8];
#pragma unroll
    for (int j = 0; j < 8; ++j) s[j] = csr_s[e + j];
#pragma unroll
    for (int j = 0; j < 8; ++j) nw[j] = dinv[s[j]] * di;
#pragma unroll
    for (int j = 0; j < 8; ++j) v[j] = xw32[(size_t)s[j] * 64 + lane];
#pragma unroll
    for (int j = 0; j < 8; ++j) {
      acc0 = fmaf(__uint_as_float(v[j] << 16), nw[j], acc0);
      acc1 = fmaf(__uint_as_float(v[j] & 0xFFFF0000u), nw[j], acc1);
    }
  }
  for (; e < end; ++e) {
    int sj = csr_s[e];
    float nwj = dinv[sj] * di;
    uint vj = xw32[(size_t)sj * 64 + lane];
    acc0 = fmaf(__uint_as_float(vj << 16), nwj, acc0);
    acc1 = fmaf(__uint_as_float(vj & 0xFFFF0000u), nwj, acc1);
  }
  // LayerNorm over 128 dims (wave-local)
  float s = acc0 + acc1;
#pragma unroll
  for (int off = 32; off > 0; off >>= 1) s += __shfl_xor(s, off);
  float mu = s * (1.f / DD);
  float c0 = acc0 - mu, c1 = acc1 - mu;
  float q = c0 * c0 + c1 * c1;
#pragma unroll
  for (int off = 32; off > 0; off >>= 1) q += __shfl_xor(q, off);
  float rstd = rsqrtf(q * (1.f / DD) + EPSV);
  float2 gv = ((const float2*)gam)[lane];
  float2 tv = ((const float2*)bet)[lane];
  float h0 = fmaf(c0 * rstd, gv.x, tv.x);
  float h1 = fmaf(c1 * rstd, gv.y, tv.y);
  float2 o;
  o.x = fmaxf(h0, 0.f);
  o.y = fmaxf(h1, 0.f);
  ((float2*)(outp + (size_t)i * DD))[lane] = o;
}

// ---------------- agg2: gather + LN + SE + residual + ReLU -> fp32 out ----------------

__global__ __launch_bounds__(256) void k_agg2(
    const ushort* __restrict__ xw, const int* __restrict__ csr_s,
    const int* __restrict__ rowoff, const int* __restrict__ deg,
    const float* __restrict__ dinv, const float* __restrict__ bias,
    const float* __restrict__ gam, const float* __restrict__ bet,
    const float* __restrict__ Ws, const float* __restrict__ bs,
    const float* __restrict__ We, const float* __restrict__ be,
    const float* __restrict__ xin, float* __restrict__ outp, int n) {
  int wv = threadIdx.x >> 6, lane = threadIdx.x & 63;
  int i = blockIdx.x * 4 + wv;
  if (i >= n) return;
  int start = rowoff[i], cnt = deg[i];
  float di = dinv[i];
  const uint* xw32 = (const uint*)xw;
  float2 bv = ((const float2*)bias)[lane];
  uint su = xw32[(size_t)i * 64 + lane];
  float sw = 2.f * di * di;
  float acc0 = fmaf(__uint_as_float(su << 16), sw, bv.x);
  float acc1 = fmaf(__uint_as_float(su & 0xFFFF0000u), sw, bv.y);
  int e = start, end = start + cnt;
  for (; e + 8 <= end; e += 8) {
    int s[8]; float nw[8]; uint v[8];
#pragma unroll
    for (int j = 0; j < 8; ++j) s[j] = csr_s[e + j];
#pragma unroll
    for (int j = 0; j < 8; ++j) nw[j] = dinv[s[j]] * di;
#pragma unroll
    for (int j = 0; j < 8; ++j) v[j] = xw32[(size_t)s[j] * 64 + lane];
#pragma unroll
    for (int j = 0; j < 8; ++j) {
      acc0 = fmaf(__uint_as_float(v[j] << 16), nw[j], acc0);
      acc1 = fmaf(__uint_as_float(v[j] & 0xFFFF0000u), nw[j], acc1);
    }
  }
  for (; e < end; ++e) {
    int sj = csr_s[e];
    float nwj = dinv[sj] * di;
    uint vj = xw32[(size_t)sj * 64 + lane];
    acc0 = fmaf(__uint_as_float(vj << 16), nwj, acc0);
    acc1 = fmaf(__uint_as_float(vj & 0xFFFF0000u), nwj, acc1);
  }
  // LayerNorm
  float s = acc0 + acc1;
#pragma unroll
  for (int off = 32; off > 0; off >>= 1) s += __shfl_xor(s, off);
  float mu = s * (1.f / DD);
  float c0 = acc0 - mu, c1 = acc1 - mu;
  float q = c0 * c0 + c1 * c1;
#pragma unroll
  for (int off = 32; off > 0; off >>= 1) q += __shfl_xor(q, off);
  float rstd = rsqrtf(q * (1.f / DD) + EPSV);
  float2 gv = ((const float2*)gam)[lane];
  float2 tv = ((const float2*)bet)[lane];
  float h0 = fmaf(c0 * rstd, gv.x, tv.x);
  float h1 = fmaf(c1 * rstd, gv.y, tv.y);
  // SE: s16 = relu(h @ Ws + bs); w = sigmoid(s16 @ We + be)
  float pj[HH];
  const float* wr0 = &Ws[(2 * lane) * HH];
  const float* wr1 = &Ws[(2 * lane + 1) * HH];
#pragma unroll
  for (int j = 0; j < HH; ++j) pj[j] = h0 * wr0[j] + h1 * wr1[j];
#pragma unroll
  for (int off = 32; off > 0; off >>= 1) {
#pragma unroll
    for (int j = 0; j < HH; ++j) pj[j] += __shfl_xor(pj[j], off);
  }
  float2 bev = ((const float2*)be)[lane];
  float wacc0 = bev.x, wacc1 = bev.y;
#pragma unroll
  for (int j = 0; j < HH; ++j) {
    float sj = fmaxf(pj[j] + bs[j], 0.f);
    float2 wev = ((const float2*)(We + j * DD))[lane];
    wacc0 = fmaf(sj, wev.x, wacc0);
    wacc1 = fmaf(sj, wev.y, wacc1);
  }
  float w0 = 1.f / (1.f + __expf(-wacc0));
  float w1 = 1.f / (1.f + __expf(-wacc1));
  float2 xr = ((const float2*)(xin + (size_t)i * DD))[lane];
  float2 o;
  o.x = fmaxf(fmaf(h0, w0, xr.x), 0.f);
  o.y = fmaxf(fmaf(h1, w1, xr.y), 0.f);
  ((float2*)(outp + (size_t)i * DD))[lane] = o;
}

// ---------------- launcher ----------------

extern "C" void kernel_launch(void* const* d_in, const int* in_sizes, int n_in,
                              void* d_out, int out_size, void* d_ws, size_t ws_size,
                              hipStream_t stream) {
  const float* x   = (const float*)d_in[0];
  const int*   ei  = (const int*)d_in[1];
  const float* W1  = (const float*)d_in[2];
  const float* b1  = (const float*)d_in[3];
  const float* g1  = (const float*)d_in[4];
  const float* be1 = (const float*)d_in[5];
  const float* W2  = (const float*)d_in[6];
  const float* b2  = (const float*)d_in[7];
  const float* g2  = (const float*)d_in[8];
  const float* be2 = (const float*)d_in[9];
  const float* Ws  = (const float*)d_in[10];
  const float* bs  = (const float*)d_in[11];
  const float* We  = (const float*)d_in[12];
  const float* bee = (const float*)d_in[13];
  float* outp = (float*)d_out;

  int n    = in_sizes[0] / DD;
  int ecnt = in_sizes[1] / 2;
  const int* src = ei;
  const int* dst = ei + ecnt;

  char* w = (char*)d_ws;
  ushort* xw    = (ushort*)w; w += (size_t)n * DD * 2;
  float*  h1    = (float*)w;  w += (size_t)n * DD * 4;
  int*    deg   = (int*)w;    w += (size_t)n * 4;
  int*    cursor= (int*)w;    w += (size_t)n * 4;  // adjacent to deg (one memset)
  int*    rowoff= (int*)w;    w += (size_t)n * 4;
  float*  dinv  = (float*)w;  w += (size_t)n * 4;
  int*    bsum  = (int*)w;    w += 64 * 4;
  int*    csr_s = (int*)w;    w += (size_t)ecnt * 4;

  hipMemsetAsync(deg, 0, (size_t)n * 8, stream);  // deg + cursor

  const int TB = 256;
  int eb = (ecnt + TB - 1) / TB;
  int nbk = (n + TB - 1) / TB;
  k_hist<<<eb, TB, 0, stream>>>(dst, deg, ecnt);
  k_dinv<<<nbk, TB, 0, stream>>>(deg, dinv, n);
  int nb = (n + SCAN_T * SCAN_I - 1) / (SCAN_T * SCAN_I);
  k_scan1<<<nb, SCAN_T, 0, stream>>>(deg, bsum, n);
  k_scan2<<<nb, SCAN_T, 0, stream>>>(deg, bsum, rowoff, n);
  k_fill<<<eb, TB, 0, stream>>>(src, dst, rowoff, cursor, csr_s, ecnt);

  dim3 gg((n + 127) / 128, 2);
  int nb4 = (n + 3) / 4;
  k_gemm<<<gg, 256, 0, stream>>>(x, W1, xw, n);
  k_agg1<<<nb4, 256, 0, stream>>>(xw, csr_s, rowoff, deg, dinv, b1, g1, be1, h1, n);
  k_gemm<<<gg, 256, 0, stream>>>(h1, W2, xw, n);
  k_agg2<<<nb4, 256, 0, stream>>>(xw, csr_s, rowoff, deg, dinv, b2, g2, be2,
                                  Ws, bs, We, bee, x, outp, n);
}

// Round 3
// 415.720 us; speedup vs baseline: 1.2683x; 1.1073x over previous
//
#include <hip/hip_runtime.h>
#include <math.h>

#define DD 128
#define HH 16
#define EPSV 1e-5f

static __device__ __forceinline__ ushort f2bf(float f) {
  uint u = __float_as_uint(f);
  u += 0x7FFFu + ((u >> 16) & 1u);
  return (ushort)(u >> 16);
}

// ---------------- CSR build ----------------

__global__ void k_hist(const int* __restrict__ dst, int* __restrict__ deg, int ecnt) {
  int e = blockIdx.x * blockDim.x + threadIdx.x;
  if (e < ecnt) atomicAdd(&deg[dst[e]], 1);
}

__global__ void k_dinv(const int* __restrict__ deg, float* __restrict__ dinv, int n) {
  int i = blockIdx.x * blockDim.x + threadIdx.x;
  if (i < n) dinv[i] = rsqrtf((float)deg[i] + 2.0f);
}

#define SCAN_T 1024
#define SCAN_I 4

__global__ void k_scan1(const int* __restrict__ deg, int* __restrict__ bsum, int n) {
  __shared__ int sh[SCAN_T];
  int tid = threadIdx.x;
  int base = blockIdx.x * SCAN_T * SCAN_I + tid * SCAN_I;
  int s = 0;
#pragma unroll
  for (int j = 0; j < SCAN_I; ++j) { int i = base + j; if (i < n) s += deg[i]; }
  sh[tid] = s;
  __syncthreads();
  for (int off = SCAN_T / 2; off > 0; off >>= 1) {
    if (tid < off) sh[tid] += sh[tid + off];
    __syncthreads();
  }
  if (tid == 0) bsum[blockIdx.x] = sh[0];
}

__global__ void k_scan2(const int* __restrict__ deg, const int* __restrict__ bsum,
                        int* __restrict__ rowoff, int n) {
  __shared__ int sh[SCAN_T];
  __shared__ int sbase;
  int tid = threadIdx.x;
  int b = blockIdx.x;
  if (tid == 0) { int s = 0; for (int j = 0; j < b; ++j) s += bsum[j]; sbase = s; }
  int base = b * SCAN_T * SCAN_I + tid * SCAN_I;
  int d[SCAN_I]; int ts = 0;
#pragma unroll
  for (int j = 0; j < SCAN_I; ++j) { int i = base + j; d[j] = (i < n) ? deg[i] : 0; ts += d[j]; }
  sh[tid] = ts;
  __syncthreads();
  for (int off = 1; off < SCAN_T; off <<= 1) {
    int v = (tid >= off) ? sh[tid - off] : 0;
    __syncthreads();
    sh[tid] += v;
    __syncthreads();
  }
  int ex = sbase + sh[tid] - ts;
#pragma unroll
  for (int j = 0; j < SCAN_I; ++j) {
    int i = base + j;
    if (i < n) rowoff[i] = ex;
    ex += d[j];
  }
}

__global__ void k_fill(const int* __restrict__ src, const int* __restrict__ dst,
                       const float* __restrict__ dinv, const int* __restrict__ rowoff,
                       int* __restrict__ cursor, int2* __restrict__ csr, int ecnt) {
  int e = blockIdx.x * blockDim.x + threadIdx.x;
  if (e >= ecnt) return;
  int s = src[e], d = dst[e];
  int p = atomicAdd(&cursor[d], 1);
  float nw = dinv[s] * dinv[d];
  csr[rowoff[d] + p] = make_int2(s, __float_as_int(nw));
}

// ---------------- GEMM: C_bf16[nrows,128] = A_f32[nrows,128] @ B[128,128] ----------------

__global__ __launch_bounds__(256) void k_gemm(const float* __restrict__ A,
                                              const float* __restrict__ B,
                                              ushort* __restrict__ C, int nrows) {
  __shared__ float Bs[DD * 64];
  int tid = threadIdx.x;
  int tx = tid & 15, ty = tid >> 4;
  int rowbase = blockIdx.x * 128;
  int c0 = blockIdx.y * 64;
  {
    int kk = tid >> 4;
    int cc = (tid & 15) * 4;
#pragma unroll
    for (int p = 0; p < 8; ++p) {
      int k = p * 16 + kk;
      float4 bv = *reinterpret_cast<const float4*>(&B[k * DD + c0 + cc]);
      *reinterpret_cast<float4*>(&Bs[k * 64 + cc]) = bv;
    }
  }
  __syncthreads();
  float acc[8][4];
#pragma unroll
  for (int i = 0; i < 8; ++i)
#pragma unroll
    for (int j = 0; j < 4; ++j) acc[i][j] = 0.f;
  int rl[8];
#pragma unroll
  for (int i = 0; i < 8; ++i) {
    int r = rowbase + ty * 8 + i;
    rl[i] = (r < nrows) ? r : (nrows - 1);
  }
  const float4* A4 = reinterpret_cast<const float4*>(A);
  for (int kq = 0; kq < 32; ++kq) {
    float4 av[8];
#pragma unroll
    for (int i = 0; i < 8; ++i) av[i] = A4[(size_t)rl[i] * 32 + kq];
#pragma unroll
    for (int j = 0; j < 4; ++j) {
      float4 bv = *reinterpret_cast<const float4*>(&Bs[(kq * 4 + j) * 64 + tx * 4]);
#pragma unroll
      for (int i = 0; i < 8; ++i) {
        float a = (j == 0) ? av[i].x : (j == 1) ? av[i].y : (j == 2) ? av[i].z : av[i].w;
        acc[i][0] = fmaf(a, bv.x, acc[i][0]);
        acc[i][1] = fmaf(a, bv.y, acc[i][1]);
        acc[i][2] = fmaf(a, bv.z, acc[i][2]);
        acc[i][3] = fmaf(a, bv.w, acc[i][3]);
      }
    }
  }
  int cbase = c0 + tx * 4;
#pragma unroll
  for (int i = 0; i < 8; ++i) {
    int r = rowbase + ty * 8 + i;
    if (r < nrows) {
      ushort4 o;
      o.x = f2bf(acc[i][0]); o.y = f2bf(acc[i][1]);
      o.z = f2bf(acc[i][2]); o.w = f2bf(acc[i][3]);
      *reinterpret_cast<ushort4*>(&C[(size_t)r * DD + cbase]) = o;
    }
  }
}

// ---------------- shared edge-accumulate (software-pipelined) ----------------
// Wave handles node i; lane owns dims {2*lane, 2*lane+1} as one packed uint.

static __device__ __forceinline__ void edge_accum(
    const uint* __restrict__ xw32, const int2* __restrict__ csr,
    int e, int rem, int lane, float& acc0, float& acc1) {
  int2 cur[8];
  if (rem >= 8) {
#pragma unroll
    for (int j = 0; j < 8; ++j) cur[j] = csr[e + j];
  }
  while (rem >= 16) {
    uint v[8];
#pragma unroll
    for (int j = 0; j < 8; ++j) v[j] = xw32[(size_t)(uint)cur[j].x * 64 + lane];
    int2 nxt[8];
#pragma unroll
    for (int j = 0; j < 8; ++j) nxt[j] = csr[e + 8 + j];
#pragma unroll
    for (int j = 0; j < 8; ++j) {
      float nw = __int_as_float(cur[j].y);
      acc0 = fmaf(__uint_as_float(v[j] << 16), nw, acc0);
      acc1 = fmaf(__uint_as_float(v[j] & 0xFFFF0000u), nw, acc1);
    }
#pragma unroll
    for (int j = 0; j < 8; ++j) cur[j] = nxt[j];
    e += 8; rem -= 8;
  }
  if (rem >= 8) {
    uint v[8];
#pragma unroll
    for (int j = 0; j < 8; ++j) v[j] = xw32[(size_t)(uint)cur[j].x * 64 + lane];
#pragma unroll
    for (int j = 0; j < 8; ++j) {
      float nw = __int_as_float(cur[j].y);
      acc0 = fmaf(__uint_as_float(v[j] << 16), nw, acc0);
      acc1 = fmaf(__uint_as_float(v[j] & 0xFFFF0000u), nw, acc1);
    }
    e += 8; rem -= 8;
  }
  if (rem >= 4) {
    int2 c4[4]; uint v[4];
#pragma unroll
    for (int j = 0; j < 4; ++j) c4[j] = csr[e + j];
#pragma unroll
    for (int j = 0; j < 4; ++j) v[j] = xw32[(size_t)(uint)c4[j].x * 64 + lane];
#pragma unroll
    for (int j = 0; j < 4; ++j) {
      float nw = __int_as_float(c4[j].y);
      acc0 = fmaf(__uint_as_float(v[j] << 16), nw, acc0);
      acc1 = fmaf(__uint_as_float(v[j] & 0xFFFF0000u), nw, acc1);
    }
    e += 4; rem -= 4;
  }
  for (; rem > 0; --rem, ++e) {
    int2 c = csr[e];
    float nw = __int_as_float(c.y);
    uint vj = xw32[(size_t)(uint)c.x * 64 + lane];
    acc0 = fmaf(__uint_as_float(vj << 16), nw, acc0);
    acc1 = fmaf(__uint_as_float(vj & 0xFFFF0000u), nw, acc1);
  }
}

// ---------------- agg1: gather bf16 + self + bias + LN + ReLU -> fp32 h1 ----------------

__global__ __launch_bounds__(256) void k_agg1(
    const ushort* __restrict__ xw, const int2* __restrict__ csr,
    const int* __restrict__ rowoff, const int* __restrict__ deg,
    const float* __restrict__ dinv, const float* __restrict__ bias,
    const float* __restrict__ gam, const float* __restrict__ bet,
    float* __restrict__ outp, int n) {
  int wv = threadIdx.x >> 6, lane = threadIdx.x & 63;
  int i = blockIdx.x * 4 + wv;
  if (i >= n) return;
  int start = rowoff[i], cnt = deg[i];
  float di = dinv[i];
  const uint* xw32 = (const uint*)xw;
  float2 bv = ((const float2*)bias)[lane];
  uint su = xw32[(size_t)i * 64 + lane];
  float sw = 2.f * di * di;
  float acc0 = fmaf(__uint_as_float(su << 16), sw, bv.x);
  float acc1 = fmaf(__uint_as_float(su & 0xFFFF0000u), sw, bv.y);
  edge_accum(xw32, csr, start, cnt, lane, acc0, acc1);
  // LayerNorm over 128 dims (wave-local)
  float s = acc0 + acc1;
#pragma unroll
  for (int off = 32; off > 0; off >>= 1) s += __shfl_xor(s, off);
  float mu = s * (1.f / DD);
  float c0 = acc0 - mu, c1 = acc1 - mu;
  float q = c0 * c0 + c1 * c1;
#pragma unroll
  for (int off = 32; off > 0; off >>= 1) q += __shfl_xor(q, off);
  float rstd = rsqrtf(q * (1.f / DD) + EPSV);
  float2 gv = ((const float2*)gam)[lane];
  float2 tv = ((const float2*)bet)[lane];
  float h0 = fmaf(c0 * rstd, gv.x, tv.x);
  float h1 = fmaf(c1 * rstd, gv.y, tv.y);
  float2 o;
  o.x = fmaxf(h0, 0.f);
  o.y = fmaxf(h1, 0.f);
  ((float2*)(outp + (size_t)i * DD))[lane] = o;
}

// ---------------- agg2: gather + LN + SE + residual + ReLU -> fp32 out ----------------

__global__ __launch_bounds__(256) void k_agg2(
    const ushort* __restrict__ xw, const int2* __restrict__ csr,
    const int* __restrict__ rowoff, const int* __restrict__ deg,
    const float* __restrict__ dinv, const float* __restrict__ bias,
    const float* __restrict__ gam, const float* __restrict__ bet,
    const float* __restrict__ Ws, const float* __restrict__ bs,
    const float* __restrict__ We, const float* __restrict__ be,
    const float* __restrict__ xin, float* __restrict__ outp, int n) {
  int wv = threadIdx.x >> 6, lane = threadIdx.x & 63;
  int i = blockIdx.x * 4 + wv;
  if (i >= n) return;
  int start = rowoff[i], cnt = deg[i];
  float di = dinv[i];
  const uint* xw32 = (const uint*)xw;
  float2 bv = ((const float2*)bias)[lane];
  uint su = xw32[(size_t)i * 64 + lane];
  float sw = 2.f * di * di;
  float acc0 = fmaf(__uint_as_float(su << 16), sw, bv.x);
  float acc1 = fmaf(__uint_as_float(su & 0xFFFF0000u), sw, bv.y);
  edge_accum(xw32, csr, start, cnt, lane, acc0, acc1);
  // LayerNorm
  float s = acc0 + acc1;
#pragma unroll
  for (int off = 32; off > 0; off >>= 1) s += __shfl_xor(s, off);
  float mu = s * (1.f / DD);
  float c0 = acc0 - mu, c1 = acc1 - mu;
  float q = c0 * c0 + c1 * c1;
#pragma unroll
  for (int off = 32; off > 0; off >>= 1) q += __shfl_xor(q, off);
  float rstd = rsqrtf(q * (1.f / DD) + EPSV);
  float2 gv = ((const float2*)gam)[lane];
  float2 tv = ((const float2*)bet)[lane];
  float h0 = fmaf(c0 * rstd, gv.x, tv.x);
  float h1 = fmaf(c1 * rstd, gv.y, tv.y);
  // SE: s16 = relu(h @ Ws + bs); w = sigmoid(s16 @ We + be)
  float pj[HH];
  const float* wr0 = &Ws[(2 * lane) * HH];
  const float* wr1 = &Ws[(2 * lane + 1) * HH];
#pragma unroll
  for (int j = 0; j < HH; ++j) pj[j] = h0 * wr0[j] + h1 * wr1[j];
#pragma unroll
  for (int off = 32; off > 0; off >>= 1) {
#pragma unroll
    for (int j = 0; j < HH; ++j) pj[j] += __shfl_xor(pj[j], off);
  }
  float2 bev = ((const float2*)be)[lane];
  float wacc0 = bev.x, wacc1 = bev.y;
#pragma unroll
  for (int j = 0; j < HH; ++j) {
    float sj = fmaxf(pj[j] + bs[j], 0.f);
    float2 wev = ((const float2*)(We + j * DD))[lane];
    wacc0 = fmaf(sj, wev.x, wacc0);
    wacc1 = fmaf(sj, wev.y, wacc1);
  }
  float w0 = 1.f / (1.f + __expf(-wacc0));
  float w1 = 1.f / (1.f + __expf(-wacc1));
  float2 xr = ((const float2*)(xin + (size_t)i * DD))[lane];
  float2 o;
  o.x = fmaxf(fmaf(h0, w0, xr.x), 0.f);
  o.y = fmaxf(fmaf(h1, w1, xr.y), 0.f);
  ((float2*)(outp + (size_t)i * DD))[lane] = o;
}

// ---------------- launcher ----------------

extern "C" void kernel_launch(void* const* d_in, const int* in_sizes, int n_in,
                              void* d_out, int out_size, void* d_ws, size_t ws_size,
                              hipStream_t stream) {
  const float* x   = (const float*)d_in[0];
  const int*   ei  = (const int*)d_in[1];
  const float* W1  = (const float*)d_in[2];
  const float* b1  = (const float*)d_in[3];
  const float* g1  = (const float*)d_in[4];
  const float* be1 = (const float*)d_in[5];
  const float* W2  = (const float*)d_in[6];
  const float* b2  = (const float*)d_in[7];
  const float* g2  = (const float*)d_in[8];
  const float* be2 = (const float*)d_in[9];
  const float* Ws  = (const float*)d_in[10];
  const float* bs  = (const float*)d_in[11];
  const float* We  = (const float*)d_in[12];
  const float* bee = (const float*)d_in[13];
  float* outp = (float*)d_out;

  int n    = in_sizes[0] / DD;
  int ecnt = in_sizes[1] / 2;
  const int* src = ei;
  const int* dst = ei + ecnt;

  char* w = (char*)d_ws;
  ushort* xw    = (ushort*)w; w += (size_t)n * DD * 2;
  float*  h1    = (float*)w;  w += (size_t)n * DD * 4;
  int*    deg   = (int*)w;    w += (size_t)n * 4;
  int*    cursor= (int*)w;    w += (size_t)n * 4;  // adjacent to deg (one memset)
  int*    rowoff= (int*)w;    w += (size_t)n * 4;
  float*  dinv  = (float*)w;  w += (size_t)n * 4;
  int*    bsum  = (int*)w;    w += 64 * 4;
  int2*   csr   = (int2*)w;   w += (size_t)ecnt * 8;

  hipMemsetAsync(deg, 0, (size_t)n * 8, stream);  // deg + cursor

  const int TB = 256;
  int eb = (ecnt + TB - 1) / TB;
  int nbk = (n + TB - 1) / TB;
  k_hist<<<eb, TB, 0, stream>>>(dst, deg, ecnt);
  k_dinv<<<nbk, TB, 0, stream>>>(deg, dinv, n);
  int nb = (n + SCAN_T * SCAN_I - 1) / (SCAN_T * SCAN_I);
  k_scan1<<<nb, SCAN_T, 0, stream>>>(deg, bsum, n);
  k_scan2<<<nb, SCAN_T, 0, stream>>>(deg, bsum, rowoff, n);
  k_fill<<<eb, TB, 0, stream>>>(src, dst, dinv, rowoff, cursor, csr, ecnt);

  dim3 gg((n + 127) / 128, 2);
  int nb4 = (n + 3) / 4;
  k_gemm<<<gg, 256, 0, stream>>>(x, W1, xw, n);
  k_agg1<<<nb4, 256, 0, stream>>>(xw, csr, rowoff, deg, dinv, b1, g1, be1, h1, n);
  k_gemm<<<gg, 256, 0, stream>>>(h1, W2, xw, n);
  k_agg2<<<nb4, 256, 0, stream>>>(xw, csr, rowoff, deg, dinv, b2, g2, be2,
                                  Ws, bs, We, bee, x, outp, n);
}